// Round 8
// baseline (285.326 us; speedup 1.0000x reference)
//
#include <hip/hip_runtime.h>
#include <math.h>

#define D_MODEL 1024
#define N_HEADS 16
#define HEAD_DIM 64
#define BATCH 4
#define SEQ 2048
#define TOKENS (BATCH * SEQ)   // 8192

typedef _Float16 f16;
typedef f16 f16x8_t __attribute__((ext_vector_type(8)));
typedef f16 f16x4_t __attribute__((ext_vector_type(4)));
typedef float f32x4_t __attribute__((ext_vector_type(4)));

// log2(e)/8 : folds the 1/sqrt(64) softmax scale and exp->exp2 into Q.
#define QSCALE 0.18033688011112042f

// attn-tile XOR-swizzle (64-wide rows): granule g of row r -> g^(r&7).
#define KSW(row, g) ((g) ^ ((row) & 7))
// GEMM-tile XOR-swizzle (32-wide rows, 64B stride): g -> g^((r>>1)&3).
// Verified: 16 lanes reading rows r..r+15 at fixed logical granule hit
// 8 bank-groups exactly 2-way (free, m136).
#define GSW(row, g) ((g) ^ (((row) >> 1) & 3))

// async global->LDS, 16B per lane; lds base wave-uniform, HW writes lane i at
// base + i*16B (m104/m108 semantics).
__device__ __forceinline__ void stage16(const f16* g, f16* l) {
    __builtin_amdgcn_global_load_lds(
        (__attribute__((address_space(1))) void*)g,
        (__attribute__((address_space(3))) void*)l, 16, 0, 0);
}

// ---------------------------------------------------------------------------
// K0: fused fp32 -> fp16 convert for X, Wqkv, Wout + RoPE cos/sin table.
// ---------------------------------------------------------------------------
#define N_X  (TOKENS * D_MODEL / 4)         // 2097152 float4s
#define N_WQ (3 * D_MODEL * D_MODEL / 4)    // 786432
#define N_WO (D_MODEL * D_MODEL / 4)        // 262144
#define N_CONV (N_X + N_WQ + N_WO)          // 3145728 (divisible by 256)
__global__ void prep_kernel(const float* __restrict__ X,
                            const float* __restrict__ Wq,
                            const float* __restrict__ Wo,
                            f16* __restrict__ Xf, f16* __restrict__ Wqf,
                            f16* __restrict__ Wof,
                            float* __restrict__ cosT, float* __restrict__ sinT) {
    int i = blockIdx.x * blockDim.x + threadIdx.x;
    if (i >= N_CONV) {
        // RoPE table, double precision source. idx in [0, SEQ*32)
        int idx = i - N_CONV;
        int s = idx >> 5;
        int ii = idx & 31;
        double t = (double)(2 * ii) / 64.0;
        double invf = pow(10000.0, -t);
        double ang = (double)s * invf;
        cosT[idx] = (float)cos(ang);
        sinT[idx] = (float)sin(ang);
        return;
    }
    const float* src;
    f16* dst;
    int j;
    if (i < N_X)             { src = X;  dst = Xf;  j = i; }
    else if (i < N_X + N_WQ) { src = Wq; dst = Wqf; j = i - N_X; }
    else                     { src = Wo; dst = Wof; j = i - N_X - N_WQ; }
    float4 x = ((const float4*)src)[j];
    f16x4_t h;
    h[0] = (f16)x.x; h[1] = (f16)x.y; h[2] = (f16)x.z; h[3] = (f16)x.w;
    ((f16x4_t*)dst)[j] = h;
}

// ---------------------------------------------------------------------------
// fp16 single-pass GEMM mainloop: C[n,c] = sum_k A[n,k]*B[c,k], fp32 accum.
// ROUND 8: BK=32 double-buffered single-barrier pipeline (attn-proven
// scheme): issue tile kt+1's global_load_lds at the top of iter kt, compute
// tile kt, then one vmcnt(0)+s_barrier per tile — loads get the whole
// compute phase to land instead of draining immediately (m233's 2-phase
// stall). LDS stays 32KB (2 bufs x [128][32] x A,B) -> 5 blocks/CU kept
// (m132 trap avoided). Source pre-swizzled GSW, linear gload_lds dest,
// GSW'd b128 fragment reads (rule #21).
// ---------------------------------------------------------------------------
#define GBK 32
#define GNKT (D_MODEL / GBK)     // 32
#define GBUF (128 * GBK)         // f16 per buffer

__device__ __forceinline__ void gemm_mainloop(
    const f16* __restrict__ A, const f16* __restrict__ B,
    int n0, int c0, f16* As, f16* Bs, f32x4_t acc[4][4]) {
    const int tid = threadIdx.x;
    const int lane = tid & 63;
    const int wave = tid >> 6;
    const int m16 = lane & 15, quad = lane >> 4;
    const int wm = (wave & 1) * 64, wn = (wave >> 1) * 64;

    // staging: lane i -> row chunk+(i>>2), physical granule i&3. Source is
    // pre-swizzled so slot (r,p) holds logical granule p^((r>>1)&3); with
    // chunks multiples of 16, (r>>1)&3 == (i>>3)&3.
    const int srow = lane >> 2;                        // 0..15
    const int sg   = (lane & 3) ^ ((lane >> 3) & 3);   // source granule

#pragma unroll
    for (int i = 0; i < 4; i++)
#pragma unroll
        for (int j = 0; j < 4; j++) acc[i][j] = (f32x4_t){0.f, 0.f, 0.f, 0.f};

    const f16* ga = A + (size_t)(n0 + wave * 32 + srow) * D_MODEL + sg * 8;
    const f16* gb = B + (size_t)(c0 + wave * 32 + srow) * D_MODEL + sg * 8;
    f16* la = As + (wave * 32) * GBK;   // wave's chunk base in buffer 0
    f16* lb = Bs + (wave * 32) * GBK;

    // prologue: stage tile 0 into buffer 0, drain, publish
    stage16(ga, la);
    stage16(ga + (size_t)16 * D_MODEL, la + 16 * GBK);
    stage16(gb, lb);
    stage16(gb + (size_t)16 * D_MODEL, lb + 16 * GBK);
    asm volatile("s_waitcnt vmcnt(0)" ::: "memory");
    __builtin_amdgcn_s_barrier();
    asm volatile("" ::: "memory");

    for (int kt = 0; kt < GNKT; kt++) {
        const int cur = kt & 1;

        if (kt + 1 < GNKT) {
            const int ko = (kt + 1) * GBK;
            const int nb = (cur ^ 1) * GBUF;
            stage16(ga + ko, la + nb);
            stage16(ga + ko + (size_t)16 * D_MODEL, la + nb + 16 * GBK);
            stage16(gb + ko, lb + nb);
            stage16(gb + ko + (size_t)16 * D_MODEL, lb + nb + 16 * GBK);
        }

        const f16* Ac = As + cur * GBUF;
        const f16* Bc = Bs + cur * GBUF;
        f16x8_t a[4], b[4];
#pragma unroll
        for (int mt = 0; mt < 4; mt++) {
            const int row = wm + mt * 16 + m16;
            a[mt] = *(const f16x8_t*)&Ac[row * GBK + GSW(row, quad) * 8];
        }
#pragma unroll
        for (int nt = 0; nt < 4; nt++) {
            const int row = wn + nt * 16 + m16;
            b[nt] = *(const f16x8_t*)&Bc[row * GBK + GSW(row, quad) * 8];
        }
        __builtin_amdgcn_s_setprio(1);
#pragma unroll
        for (int mt = 0; mt < 4; mt++)
#pragma unroll
            for (int nt = 0; nt < 4; nt++)
                acc[mt][nt] = __builtin_amdgcn_mfma_f32_16x16x32_f16(
                    a[mt], b[nt], acc[mt][nt], 0, 0, 0);
        __builtin_amdgcn_s_setprio(0);

        // drain own next-tile loads (landed under the compute), publish
        asm volatile("s_waitcnt vmcnt(0)" ::: "memory");
        __builtin_amdgcn_s_barrier();
        asm volatile("" ::: "memory");
    }
}

// ---------------------------------------------------------------------------
// K1: QKV projection (fp16 MFMA) + bias + in-register RoPE.
// Q: (B,H,S,Dh) pre-scaled by log2e/8.  K: (B,H,S,Dh).
// V: TRANSPOSED (B,H,Dh,S) with tokens PERMUTED inside each 32-token block:
//   token s (s%32 = h*16 + quad*4 + i) -> pos (s & ~31) + quad*8 + h*4 + i.
// This makes each attn lane's 8 PV keys one contiguous 16B LDS granule.
// ---------------------------------------------------------------------------
__global__ __launch_bounds__(256)
void qkv_gemm_kernel(const f16* __restrict__ Xf, const f16* __restrict__ Wf,
                     const float* __restrict__ bias,
                     f16* __restrict__ Qb, f16* __restrict__ Kb,
                     f16* __restrict__ VbT,
                     const float* __restrict__ cosT, const float* __restrict__ sinT) {
    __shared__ f16 As[2 * GBUF];
    __shared__ f16 Bs[2 * GBUF];
    f32x4_t acc[4][4];
    const int n0 = blockIdx.y * 128;
    const int c0 = blockIdx.x * 128;
    gemm_mainloop(Xf, Wf, n0, c0, As, Bs, acc);

    const int lane = threadIdx.x & 63;
    const int wave = threadIdx.x >> 6;
    const int m16 = lane & 15, quad = lane >> 4;
    const int wm = (wave & 1) * 64, wn = (wave >> 1) * 64;

    const int w = c0 >> 10;                     // 0=q,1=k,2=v (block-uniform)
    const int hh = ((c0 + wn) & 1023) >> 6;     // head (wave-uniform)
    const int b = n0 >> 11;                     // block-uniform

    float bias4[4];
#pragma unroll
    for (int nt = 0; nt < 4; nt++) bias4[nt] = bias[c0 + wn + nt * 16 + m16];

    if (w == 2) {
        // V^T store with in-block token permutation (see header comment).
        f16* vbase = VbT + ((size_t)(b * N_HEADS + hh) * HEAD_DIM) * SEQ;
#pragma unroll
        for (int mt = 0; mt < 4; mt++) {
            const int sbl = (n0 + wm + (mt >> 1) * 32) & (SEQ - 1);
            const int sb  = sbl + quad * 8 + (mt & 1) * 4;
#pragma unroll
            for (int nt = 0; nt < 4; nt++) {
                const int dh = nt * 16 + m16;
                f16x4_t v4;
#pragma unroll
                for (int i = 0; i < 4; i++) v4[i] = (f16)(acc[mt][nt][i] + bias4[nt]);
                *(f16x4_t*)&vbase[(size_t)dh * SEQ + sb] = v4;
            }
        }
        return;
    }

    f16* dst = (w == 0) ? Qb : Kb;
#pragma unroll
    for (int mt = 0; mt < 4; mt++)
#pragma unroll
        for (int i = 0; i < 4; i++) {
            const int n = n0 + wm + mt * 16 + quad * 4 + i;
            const int s = n & (SEQ - 1);
            f16* drow = dst + ((size_t)(b * N_HEADS + hh) * SEQ + s) * HEAD_DIM;
            float vv[4];
#pragma unroll
            for (int nt = 0; nt < 4; nt++) vv[nt] = acc[mt][nt][i] + bias4[nt];
            const float cs0 = cosT[(s << 5) + m16];
            const float sn0 = sinT[(s << 5) + m16];
            const float cs1 = cosT[(s << 5) + 16 + m16];
            const float sn1 = sinT[(s << 5) + 16 + m16];
#pragma unroll
            for (int nt = 0; nt < 4; nt++) {
                const int dh = nt * 16 + m16;
                const float cs = (nt & 1) ? cs1 : cs0;
                const float sn = (nt & 1) ? sn1 : sn0;
                const float part = vv[nt ^ 2];
                float outv = (nt >= 2) ? fmaf(vv[nt], cs, part * sn)
                                       : fmaf(vv[nt], cs, -part * sn);
                if (w == 0) outv *= QSCALE;
                drow[dh] = (f16)outv;
            }
        }
}

// ---------------------------------------------------------------------------
// K3: output projection (fp16 MFMA) + bias -> fp32 d_out.
// ---------------------------------------------------------------------------
__global__ __launch_bounds__(256)
void out_gemm_kernel(const f16* __restrict__ Of, const f16* __restrict__ Wf,
                     const float* __restrict__ bias, float* __restrict__ Cout) {
    __shared__ f16 As[2 * GBUF];
    __shared__ f16 Bs[2 * GBUF];
    f32x4_t acc[4][4];
    const int n0 = blockIdx.y * 128;
    const int c0 = blockIdx.x * 128;
    gemm_mainloop(Of, Wf, n0, c0, As, Bs, acc);

    const int lane = threadIdx.x & 63;
    const int wave = threadIdx.x >> 6;
    const int m16 = lane & 15, quad = lane >> 4;
    const int wm = (wave & 1) * 64, wn = (wave >> 1) * 64;

    float bias4[4];
#pragma unroll
    for (int nt = 0; nt < 4; nt++) bias4[nt] = bias[c0 + wn + nt * 16 + m16];

#pragma unroll
    for (int mt = 0; mt < 4; mt++)
#pragma unroll
        for (int i = 0; i < 4; i++) {
            const int n = n0 + wm + mt * 16 + quad * 4 + i;
            float* orow = Cout + (size_t)n * D_MODEL + c0 + wn;
#pragma unroll
            for (int nt = 0; nt < 4; nt++)
                orow[nt * 16 + m16] = acc[mt][nt][i] + bias4[nt];
        }
}

// ---------------------------------------------------------------------------
// K2: flash attention, fp16 MFMA, S^T formulation, fixed-max softmax.
// EXACT round-6 version (6 consecutive passes, 84us): QBLK=256, 4 waves x
// 64q, P in registers (lane-local pack), dbuf K/V with single barrier/tile,
// V-permute b128 PV reads, 0 bank conflicts, VALU sumacc + shfl-reduce
// epilogue. (Round-7's MFMA-denominator variant diverged on graph replays
// and is reverted — mechanism unresolved, do not re-ship.)
// ---------------------------------------------------------------------------
#define NT (SEQ / 64)
__global__ __launch_bounds__(256, 2)
void attn_kernel(const f16* __restrict__ Qb, const f16* __restrict__ Kb,
                 const f16* __restrict__ VbT, f16* __restrict__ Of) {
    __shared__ f16 Ks[2][64 * 64];    // [buf][key][granule-swizzled d]
    __shared__ f16 Vs[2][64 * 64];    // [buf][d][granule-swizzled perm-key]

    const int tid  = threadIdx.x;
    const int lane = tid & 63;
    const int wave = tid >> 6;
    const int m16  = lane & 15;
    const int quad = lane >> 4;

    const int bh = blockIdx.x & 63;      // head id (XCD = bh % 8)
    const int qt = blockIdx.x >> 6;      // 0..7
    const int s0 = qt * 256;

    const f16* Kbase  = Kb + (size_t)bh * SEQ * HEAD_DIM;
    const f16* VtBase = VbT + (size_t)bh * HEAD_DIM * SEQ;

    // Q B-frags: B[n=q][k=quad*8+j], q = s0 + wave*64 + nq*16 + m16
    f16x8_t bq[4][2];
#pragma unroll
    for (int nq = 0; nq < 4; nq++) {
        const f16* qrow = Qb + ((size_t)bh * SEQ + s0 + wave * 64 + nq * 16 + m16)
                          * HEAD_DIM + quad * 8;
        bq[nq][0] = *(const f16x8_t*)(qrow);
        bq[nq][1] = *(const f16x8_t*)(qrow + 32);
    }

    f32x4_t Oc[4][4];
#pragma unroll
    for (int mt = 0; mt < 4; mt++)
#pragma unroll
        for (int nq = 0; nq < 4; nq++) Oc[mt][nq] = (f32x4_t){0.f, 0.f, 0.f, 0.f};
    float sumacc[4] = {0.f, 0.f, 0.f, 0.f};

    // staging: wave w covers rows [w*16, w*16+16) of both tiles, 2 calls each
    const int lrow0 = wave * 16 + (lane >> 3);
    const int lrow1 = lrow0 + 8;
    const int gK0 = lrow0 * HEAD_DIM + KSW(lrow0, lane & 7) * 8;
    const int gK1 = lrow1 * HEAD_DIM + KSW(lrow1, lane & 7) * 8;
    const int gV0 = lrow0 * SEQ + KSW(lrow0, lane & 7) * 8;
    const int gV1 = lrow1 * SEQ + KSW(lrow1, lane & 7) * 8;
    const int lO0 = (wave * 16) * 64;       // wave-uniform LDS base offsets
    const int lO1 = (wave * 16 + 8) * 64;

    // prologue: stage tile 0 into buffer 0, drain, publish
    stage16(Kbase + gK0, &Ks[0][lO0]);
    stage16(Kbase + gK1, &Ks[0][lO1]);
    stage16(VtBase + gV0, &Vs[0][lO0]);
    stage16(VtBase + gV1, &Vs[0][lO1]);
    asm volatile("s_waitcnt vmcnt(0)" ::: "memory");
    __builtin_amdgcn_s_barrier();
    asm volatile("" ::: "memory");

    for (int kt = 0; kt < NT; kt++) {
        const int cur = kt & 1;

        // issue next tile's staging into the other buffer
        if (kt + 1 < NT) {
            const f16* kg = Kbase + (size_t)(kt + 1) * 64 * HEAD_DIM;
            const f16* vg = VtBase + (kt + 1) * 64;
            f16* kd = &Ks[cur ^ 1][0];
            f16* vd = &Vs[cur ^ 1][0];
            stage16(kg + gK0, kd + lO0);
            stage16(kg + gK1, kd + lO1);
            stage16(vg + gV0, vd + lO0);
            stage16(vg + gV1, vd + lO1);
        }

        const f16* Kc = &Ks[cur][0];
        const f16* Vc = &Vs[cur][0];

        // --- S^T = K Q^T: per wave 64 keys x 64 q ---
        f32x4_t Sc[4][4];
#pragma unroll
        for (int nt = 0; nt < 4; nt++)
#pragma unroll
            for (int nq = 0; nq < 4; nq++) Sc[nt][nq] = (f32x4_t){0.f, 0.f, 0.f, 0.f};
#pragma unroll
        for (int kki = 0; kki < 2; kki++) {
#pragma unroll
            for (int nt = 0; nt < 4; nt++) {
                const int row = nt * 16 + m16;   // key row
                f16x8_t ak = *(const f16x8_t*)&Kc[row * 64 + KSW(row, kki * 4 + quad) * 8];
                __builtin_amdgcn_s_setprio(1);
#pragma unroll
                for (int nq = 0; nq < 4; nq++)
                    Sc[nt][nq] = __builtin_amdgcn_mfma_f32_16x16x32_f16(
                        ak, bq[nq][kki], Sc[nt][nq], 0, 0, 0);
                __builtin_amdgcn_s_setprio(0);
            }
        }

        // --- per 32-key half: exp2 + lane-local pack -> bp, then PV ---
#pragma unroll
        for (int kki = 0; kki < 2; kki++) {
            f16x8_t bp[4];
#pragma unroll
            for (int nq = 0; nq < 4; nq++)
#pragma unroll
                for (int h = 0; h < 2; h++) {
                    const int nt = 2 * kki + h;
#pragma unroll
                    for (int i = 0; i < 4; i++) {
                        float p = __builtin_amdgcn_exp2f(Sc[nt][nq][i]);
                        sumacc[nq] += p;
                        bp[nq][h * 4 + i] = (f16)p;
                    }
                }
            // O^T += V^T P^T over this 32-key half; permuted token order
            // makes the lane's 8 keys one contiguous swizzled granule.
#pragma unroll
            for (int mt = 0; mt < 4; mt++) {
                const int d = mt * 16 + m16;
                f16x8_t av = *(const f16x8_t*)&Vc[d * 64 + KSW(d, kki * 4 + quad) * 8];
                __builtin_amdgcn_s_setprio(1);
#pragma unroll
                for (int nq = 0; nq < 4; nq++)
                    Oc[mt][nq] = __builtin_amdgcn_mfma_f32_16x16x32_f16(
                        av, bp[nq], Oc[mt][nq], 0, 0, 0);
                __builtin_amdgcn_s_setprio(0);
            }
        }

        // drain own next-tile loads, then one barrier publishes all staging
        asm volatile("s_waitcnt vmcnt(0)" ::: "memory");
        __builtin_amdgcn_s_barrier();
        asm volatile("" ::: "memory");
    }

    // --- l reduction across quads (lanes sharing m16), epilogue ---
    const int b = bh >> 4, h = bh & 15;
#pragma unroll
    for (int nq = 0; nq < 4; nq++) {
        float l = sumacc[nq];
        l += __shfl_xor(l, 16);
        l += __shfl_xor(l, 32);
        const float invl = 1.0f / l;
        const int s = s0 + wave * 64 + nq * 16 + m16;
        const size_t off = ((size_t)(b * SEQ + s)) * D_MODEL + h * HEAD_DIM;
#pragma unroll
        for (int mt = 0; mt < 4; mt++) {
            f16x4_t o4;
#pragma unroll
            for (int i = 0; i < 4; i++)
                o4[i] = (f16)(Oc[mt][nq][i] * invl);
            *(f16x4_t*)&Of[off + mt * 16 + quad * 4] = o4;
        }
    }
}

// ---------------------------------------------------------------------------
extern "C" void kernel_launch(void* const* d_in, const int* in_sizes, int n_in,
                              void* d_out, int out_size, void* d_ws, size_t ws_size,
                              hipStream_t stream) {
    const float* X    = (const float*)d_in[0];
    const float* Wqkv = (const float*)d_in[1];
    const float* bqkv = (const float*)d_in[2];
    const float* Wout = (const float*)d_in[3];
    const float* bout = (const float*)d_in[4];
    float* out = (float*)d_out;

    char* w8 = (char*)d_ws;
    const size_t MB = 1024 * 1024;
    f16* Xf  = (f16*)(w8);                 // 16 MB
    f16* Wqf = (f16*)(w8 + 16 * MB);       // 6 MB
    f16* Wof = (f16*)(w8 + 22 * MB);       // 2 MB
    f16* Qf  = (f16*)(w8 + 24 * MB);       // 16 MB
    f16* Kf  = (f16*)(w8 + 40 * MB);       // 16 MB
    f16* VfT = (f16*)(w8 + 56 * MB);       // 16 MB, (B,H,Dh,S) perm-tokens
    f16* Of  = (f16*)(w8 + 72 * MB);       // 16 MB
    float* cosT = (float*)(w8 + 88 * MB);  // 256 KB
    float* sinT = cosT + SEQ * 32;         // 256 KB

    prep_kernel<<<(N_CONV + SEQ * 32) / 256, 256, 0, stream>>>(
        X, Wqkv, Wout, Xf, Wqf, Wof, cosT, sinT);

    qkv_gemm_kernel<<<dim3(3 * D_MODEL / 128, TOKENS / 128), 256, 0, stream>>>(
        Xf, Wqf, bqkv, Qf, Kf, VfT, cosT, sinT);
    attn_kernel<<<64 * (SEQ / 256), 256, 0, stream>>>(Qf, Kf, VfT, Of);
    out_gemm_kernel<<<dim3(D_MODEL / 128, TOKENS / 128), 256, 0, stream>>>(
        Of, Wof, bout, out);
}

// Round 9
// 254.256 us; speedup vs baseline: 1.1222x; 1.1222x over previous
//
#include <hip/hip_runtime.h>
#include <math.h>

#define D_MODEL 1024
#define N_HEADS 16
#define HEAD_DIM 64
#define BATCH 4
#define SEQ 2048
#define TOKENS (BATCH * SEQ)   // 8192

typedef _Float16 f16;
typedef f16 f16x8_t __attribute__((ext_vector_type(8)));
typedef f16 f16x4_t __attribute__((ext_vector_type(4)));
typedef float f32x4_t __attribute__((ext_vector_type(4)));

// log2(e)/8 : folds the 1/sqrt(64) softmax scale and exp->exp2 into Q.
#define QSCALE 0.18033688011112042f

// XOR-swizzle: granule g of row r lives at LDS granule g^(r&7).
// Breaks the 128B-row-stride same-bank pattern (16-way -> conflict-free).
#define KSW(row, g) ((g) ^ ((row) & 7))

// async global->LDS, 16B per lane; lds base wave-uniform, HW writes lane i at
// base + i*16B (m104/m108 semantics).
__device__ __forceinline__ void stage16(const f16* g, f16* l) {
    __builtin_amdgcn_global_load_lds(
        (__attribute__((address_space(1))) void*)g,
        (__attribute__((address_space(3))) void*)l, 16, 0, 0);
}

// ---------------------------------------------------------------------------
// K0: fused fp32 -> fp16 convert for X, Wqkv, Wout + RoPE cos/sin table.
// ---------------------------------------------------------------------------
#define N_X  (TOKENS * D_MODEL / 4)         // 2097152 float4s
#define N_WQ (3 * D_MODEL * D_MODEL / 4)    // 786432
#define N_WO (D_MODEL * D_MODEL / 4)        // 262144
#define N_CONV (N_X + N_WQ + N_WO)          // 3145728 (divisible by 256)
__global__ void prep_kernel(const float* __restrict__ X,
                            const float* __restrict__ Wq,
                            const float* __restrict__ Wo,
                            f16* __restrict__ Xf, f16* __restrict__ Wqf,
                            f16* __restrict__ Wof,
                            float* __restrict__ cosT, float* __restrict__ sinT) {
    int i = blockIdx.x * blockDim.x + threadIdx.x;
    if (i >= N_CONV) {
        // RoPE table, double precision source. idx in [0, SEQ*32)
        int idx = i - N_CONV;
        int s = idx >> 5;
        int ii = idx & 31;
        double t = (double)(2 * ii) / 64.0;
        double invf = pow(10000.0, -t);
        double ang = (double)s * invf;
        cosT[idx] = (float)cos(ang);
        sinT[idx] = (float)sin(ang);
        return;
    }
    const float* src;
    f16* dst;
    int j;
    if (i < N_X)             { src = X;  dst = Xf;  j = i; }
    else if (i < N_X + N_WQ) { src = Wq; dst = Wqf; j = i - N_X; }
    else                     { src = Wo; dst = Wof; j = i - N_X - N_WQ; }
    float4 x = ((const float4*)src)[j];
    f16x4_t h;
    h[0] = (f16)x.x; h[1] = (f16)x.y; h[2] = (f16)x.z; h[3] = (f16)x.w;
    ((f16x4_t*)dst)[j] = h;
}

// ---------------------------------------------------------------------------
// fp16 GEMM mainloop, r3-proven version (used by out_gemm): 128x128 tile,
// BK=64, 4 waves x (4x4 of 16x16x32 MFMA f16), global_load_lds, KSW swizzle
// via pre-swizzled GLOBAL source + swizzled fragment reads (rule #21).
// ---------------------------------------------------------------------------
__device__ __forceinline__ void gemm_mainloop(
    const f16* __restrict__ A, const f16* __restrict__ B,
    int n0, int c0, f16* As, f16* Bs, f32x4_t acc[4][4]) {
    const int tid = threadIdx.x;
    const int lane = tid & 63;
    const int wave = tid >> 6;
    const int m16 = lane & 15, quad = lane >> 4;
    const int wm = (wave & 1) * 64, wn = (wave >> 1) * 64;

    const int srow  = lane >> 3;                 // 0..7 (== row&7 per chunk)
    const int sgran = (lane & 7) ^ srow;         // inverse-swizzled src granule

#pragma unroll
    for (int i = 0; i < 4; i++)
#pragma unroll
        for (int j = 0; j < 4; j++) acc[i][j] = (f32x4_t){0.f, 0.f, 0.f, 0.f};

    f16* ldsA = As + (wave * 32) * 64;
    f16* ldsB = Bs + (wave * 32) * 64;
    const f16* ga = A + (size_t)(n0 + wave * 32 + srow) * D_MODEL + sgran * 8;
    const f16* gb = B + (size_t)(c0 + wave * 32 + srow) * D_MODEL + sgran * 8;

    for (int kt = 0; kt < 16; kt++) {
        const int ko = kt * 64;
        __syncthreads();
#pragma unroll
        for (int inst = 0; inst < 4; inst++) {
            stage16(ga + ko + (size_t)(inst * 8) * D_MODEL, ldsA + inst * 8 * 64);
            stage16(gb + ko + (size_t)(inst * 8) * D_MODEL, ldsB + inst * 8 * 64);
        }
        __syncthreads();
#pragma unroll
        for (int kk = 0; kk < 2; kk++) {
            f16x8_t a[4], b[4];
#pragma unroll
            for (int mt = 0; mt < 4; mt++) {
                const int row = wm + mt * 16 + m16;
                a[mt] = *(const f16x8_t*)&As[row * 64 + KSW(row, kk * 4 + quad) * 8];
            }
#pragma unroll
            for (int nt = 0; nt < 4; nt++) {
                const int row = wn + nt * 16 + m16;
                b[nt] = *(const f16x8_t*)&Bs[row * 64 + KSW(row, kk * 4 + quad) * 8];
            }
#pragma unroll
            for (int mt = 0; mt < 4; mt++)
#pragma unroll
                for (int nt = 0; nt < 4; nt++)
                    acc[mt][nt] = __builtin_amdgcn_mfma_f32_16x16x32_f16(
                        a[mt], b[nt], acc[mt][nt], 0, 0, 0);
        }
    }
}

// ---------------------------------------------------------------------------
// K1: QKV projection + bias + in-register RoPE.
// ROUND 9: 256x128 tile, 8 waves (512 thr), single 48KB LDS buffer, same
// r3-proven 2-barrier/BK=64 schedule. Per-wave ds_read/MFMA unchanged
// (16 b128 / 32 MFMA per K-step) but staging drops 8 -> 6 stage16 calls
// (-25% staged bytes per output), attacking the m233 stage+drain term.
// Wave (m,n) split: wm=(wave&3)*64, wn=(wave>>2)*64.
// V: TRANSPOSED (B,H,Dh,S) with tokens PERMUTED inside each 32-token block:
//   token s (s%32 = h*16 + quad*4 + i) -> pos (s & ~31) + quad*8 + h*4 + i.
// ---------------------------------------------------------------------------
__global__ __launch_bounds__(512)
void qkv_gemm_kernel(const f16* __restrict__ Xf, const f16* __restrict__ Wf,
                     const float* __restrict__ bias,
                     f16* __restrict__ Qb, f16* __restrict__ Kb,
                     f16* __restrict__ VbT,
                     const float* __restrict__ cosT, const float* __restrict__ sinT) {
    __shared__ f16 Ts[384 * 64];      // rows 0-255 = A (X), rows 256-383 = B (W)

    const int tid = threadIdx.x;
    const int lane = tid & 63;
    const int wave = tid >> 6;        // 0..7
    const int m16 = lane & 15, quad = lane >> 4;
    const int wm = (wave & 3) * 64, wn = (wave >> 2) * 64;

    const int n0 = blockIdx.y * 256;
    const int c0 = blockIdx.x * 128;

    const int srow8 = lane >> 3;                 // 0..7 (== row&7)
    const int sgran = (lane & 7) ^ srow8;        // inverse-swizzled src granule

    f32x4_t acc[4][4];
#pragma unroll
    for (int i = 0; i < 4; i++)
#pragma unroll
        for (int j = 0; j < 4; j++) acc[i][j] = (f32x4_t){0.f, 0.f, 0.f, 0.f};

    // staging: call j (j<4 -> A panel j, j>=4 -> B panel j-4); within a
    // panel, wave w covers rows w*8..w*8+8. LDS dst is wave-uniform base
    // + lane*16B (linear, rule #21); source granule pre-swizzled.
    const f16* ga = Xf + (size_t)(n0 + wave * 8 + srow8) * D_MODEL + sgran * 8;
    const f16* gb = Wf + (size_t)(c0 + wave * 8 + srow8) * D_MODEL + sgran * 8;
    f16* lbase = Ts + (wave * 8) * 64;

    for (int kt = 0; kt < 16; kt++) {
        const int ko = kt * 64;
        __syncthreads();
#pragma unroll
        for (int j = 0; j < 4; j++)
            stage16(ga + ko + (size_t)(j * 64) * D_MODEL, lbase + (j * 64) * 64);
#pragma unroll
        for (int j = 0; j < 2; j++)
            stage16(gb + ko + (size_t)(j * 64) * D_MODEL, lbase + ((4 + j) * 64) * 64);
        __syncthreads();
#pragma unroll
        for (int kk = 0; kk < 2; kk++) {
            f16x8_t a[4], b[4];
#pragma unroll
            for (int mt = 0; mt < 4; mt++) {
                const int row = wm + mt * 16 + m16;
                a[mt] = *(const f16x8_t*)&Ts[row * 64 + KSW(row, kk * 4 + quad) * 8];
            }
#pragma unroll
            for (int nt = 0; nt < 4; nt++) {
                const int row = 256 + wn + nt * 16 + m16;
                b[nt] = *(const f16x8_t*)&Ts[row * 64 + KSW(row, kk * 4 + quad) * 8];
            }
            __builtin_amdgcn_s_setprio(1);
#pragma unroll
            for (int mt = 0; mt < 4; mt++)
#pragma unroll
                for (int nt = 0; nt < 4; nt++)
                    acc[mt][nt] = __builtin_amdgcn_mfma_f32_16x16x32_f16(
                        a[mt], b[nt], acc[mt][nt], 0, 0, 0);
            __builtin_amdgcn_s_setprio(0);
        }
    }

    const int w = c0 >> 10;                     // 0=q,1=k,2=v (block-uniform)
    const int hh = ((c0 + wn) & 1023) >> 6;     // head (wave-uniform)
    const int b = n0 >> 11;                     // block-uniform (256 | 2048)

    float bias4[4];
#pragma unroll
    for (int nt = 0; nt < 4; nt++) bias4[nt] = bias[c0 + wn + nt * 16 + m16];

    if (w == 2) {
        // V^T store with in-block token permutation (see header comment).
        f16* vbase = VbT + ((size_t)(b * N_HEADS + hh) * HEAD_DIM) * SEQ;
#pragma unroll
        for (int mt = 0; mt < 4; mt++) {
            const int sbl = (n0 + wm + (mt >> 1) * 32) & (SEQ - 1);
            const int sb  = sbl + quad * 8 + (mt & 1) * 4;
#pragma unroll
            for (int nt = 0; nt < 4; nt++) {
                const int dh = nt * 16 + m16;
                f16x4_t v4;
#pragma unroll
                for (int i = 0; i < 4; i++) v4[i] = (f16)(acc[mt][nt][i] + bias4[nt]);
                *(f16x4_t*)&vbase[(size_t)dh * SEQ + sb] = v4;
            }
        }
        return;
    }

    f16* dst = (w == 0) ? Qb : Kb;
#pragma unroll
    for (int mt = 0; mt < 4; mt++)
#pragma unroll
        for (int i = 0; i < 4; i++) {
            const int n = n0 + wm + mt * 16 + quad * 4 + i;
            const int s = n & (SEQ - 1);
            f16* drow = dst + ((size_t)(b * N_HEADS + hh) * SEQ + s) * HEAD_DIM;
            float vv[4];
#pragma unroll
            for (int nt = 0; nt < 4; nt++) vv[nt] = acc[mt][nt][i] + bias4[nt];
            const float cs0 = cosT[(s << 5) + m16];
            const float sn0 = sinT[(s << 5) + m16];
            const float cs1 = cosT[(s << 5) + 16 + m16];
            const float sn1 = sinT[(s << 5) + 16 + m16];
#pragma unroll
            for (int nt = 0; nt < 4; nt++) {
                const int dh = nt * 16 + m16;
                const float cs = (nt & 1) ? cs1 : cs0;
                const float sn = (nt & 1) ? sn1 : sn0;
                const float part = vv[nt ^ 2];
                float outv = (nt >= 2) ? fmaf(vv[nt], cs, part * sn)
                                       : fmaf(vv[nt], cs, -part * sn);
                if (w == 0) outv *= QSCALE;
                drow[dh] = (f16)outv;
            }
        }
}

// ---------------------------------------------------------------------------
// K3: output projection (fp16 MFMA) + bias -> fp32 d_out. (r3-proven 128².)
// ---------------------------------------------------------------------------
__global__ __launch_bounds__(256)
void out_gemm_kernel(const f16* __restrict__ Of, const f16* __restrict__ Wf,
                     const float* __restrict__ bias, float* __restrict__ Cout) {
    __shared__ f16 As[128 * 64];
    __shared__ f16 Bs[128 * 64];
    f32x4_t acc[4][4];
    const int n0 = blockIdx.y * 128;
    const int c0 = blockIdx.x * 128;
    gemm_mainloop(Of, Wf, n0, c0, As, Bs, acc);

    const int lane = threadIdx.x & 63;
    const int wave = threadIdx.x >> 6;
    const int m16 = lane & 15, quad = lane >> 4;
    const int wm = (wave & 1) * 64, wn = (wave >> 1) * 64;

    float bias4[4];
#pragma unroll
    for (int nt = 0; nt < 4; nt++) bias4[nt] = bias[c0 + wn + nt * 16 + m16];

#pragma unroll
    for (int mt = 0; mt < 4; mt++)
#pragma unroll
        for (int i = 0; i < 4; i++) {
            const int n = n0 + wm + mt * 16 + quad * 4 + i;
            float* orow = Cout + (size_t)n * D_MODEL + c0 + wn;
#pragma unroll
            for (int nt = 0; nt < 4; nt++)
                orow[nt * 16 + m16] = acc[mt][nt][i] + bias4[nt];
        }
}

// ---------------------------------------------------------------------------
// K2: flash attention, fp16 MFMA, S^T formulation, fixed-max softmax.
// EXACT round-6 version (verified passing, ~84us): QBLK=256, 4 waves x 64q,
// P in registers (lane-local pack), dbuf K/V with single barrier/tile,
// V-permute b128 PV reads, 0 bank conflicts, VALU sumacc + shfl epilogue.
// ---------------------------------------------------------------------------
#define NT (SEQ / 64)
__global__ __launch_bounds__(256, 2)
void attn_kernel(const f16* __restrict__ Qb, const f16* __restrict__ Kb,
                 const f16* __restrict__ VbT, f16* __restrict__ Of) {
    __shared__ f16 Ks[2][64 * 64];    // [buf][key][granule-swizzled d]
    __shared__ f16 Vs[2][64 * 64];    // [buf][d][granule-swizzled perm-key]

    const int tid  = threadIdx.x;
    const int lane = tid & 63;
    const int wave = tid >> 6;
    const int m16  = lane & 15;
    const int quad = lane >> 4;

    const int bh = blockIdx.x & 63;      // head id (XCD = bh % 8)
    const int qt = blockIdx.x >> 6;      // 0..7
    const int s0 = qt * 256;

    const f16* Kbase  = Kb + (size_t)bh * SEQ * HEAD_DIM;
    const f16* VtBase = VbT + (size_t)bh * HEAD_DIM * SEQ;

    // Q B-frags: B[n=q][k=quad*8+j], q = s0 + wave*64 + nq*16 + m16
    f16x8_t bq[4][2];
#pragma unroll
    for (int nq = 0; nq < 4; nq++) {
        const f16* qrow = Qb + ((size_t)bh * SEQ + s0 + wave * 64 + nq * 16 + m16)
                          * HEAD_DIM + quad * 8;
        bq[nq][0] = *(const f16x8_t*)(qrow);
        bq[nq][1] = *(const f16x8_t*)(qrow + 32);
    }

    f32x4_t Oc[4][4];
#pragma unroll
    for (int mt = 0; mt < 4; mt++)
#pragma unroll
        for (int nq = 0; nq < 4; nq++) Oc[mt][nq] = (f32x4_t){0.f, 0.f, 0.f, 0.f};
    float sumacc[4] = {0.f, 0.f, 0.f, 0.f};

    // staging: wave w covers rows [w*16, w*16+16) of both tiles, 2 calls each
    const int lrow0 = wave * 16 + (lane >> 3);
    const int lrow1 = lrow0 + 8;
    const int gK0 = lrow0 * HEAD_DIM + KSW(lrow0, lane & 7) * 8;
    const int gK1 = lrow1 * HEAD_DIM + KSW(lrow1, lane & 7) * 8;
    const int gV0 = lrow0 * SEQ + KSW(lrow0, lane & 7) * 8;
    const int gV1 = lrow1 * SEQ + KSW(lrow1, lane & 7) * 8;
    const int lO0 = (wave * 16) * 64;       // wave-uniform LDS base offsets
    const int lO1 = (wave * 16 + 8) * 64;

    // prologue: stage tile 0 into buffer 0, drain, publish
    stage16(Kbase + gK0, &Ks[0][lO0]);
    stage16(Kbase + gK1, &Ks[0][lO1]);
    stage16(VtBase + gV0, &Vs[0][lO0]);
    stage16(VtBase + gV1, &Vs[0][lO1]);
    asm volatile("s_waitcnt vmcnt(0)" ::: "memory");
    __builtin_amdgcn_s_barrier();
    asm volatile("" ::: "memory");

    for (int kt = 0; kt < NT; kt++) {
        const int cur = kt & 1;

        // issue next tile's staging into the other buffer
        if (kt + 1 < NT) {
            const f16* kg = Kbase + (size_t)(kt + 1) * 64 * HEAD_DIM;
            const f16* vg = VtBase + (kt + 1) * 64;
            f16* kd = &Ks[cur ^ 1][0];
            f16* vd = &Vs[cur ^ 1][0];
            stage16(kg + gK0, kd + lO0);
            stage16(kg + gK1, kd + lO1);
            stage16(vg + gV0, vd + lO0);
            stage16(vg + gV1, vd + lO1);
        }

        const f16* Kc = &Ks[cur][0];
        const f16* Vc = &Vs[cur][0];

        // --- S^T = K Q^T: per wave 64 keys x 64 q ---
        f32x4_t Sc[4][4];
#pragma unroll
        for (int nt = 0; nt < 4; nt++)
#pragma unroll
            for (int nq = 0; nq < 4; nq++) Sc[nt][nq] = (f32x4_t){0.f, 0.f, 0.f, 0.f};
#pragma unroll
        for (int kki = 0; kki < 2; kki++) {
#pragma unroll
            for (int nt = 0; nt < 4; nt++) {
                const int row = nt * 16 + m16;   // key row
                f16x8_t ak = *(const f16x8_t*)&Kc[row * 64 + KSW(row, kki * 4 + quad) * 8];
                __builtin_amdgcn_s_setprio(1);
#pragma unroll
                for (int nq = 0; nq < 4; nq++)
                    Sc[nt][nq] = __builtin_amdgcn_mfma_f32_16x16x32_f16(
                        ak, bq[nq][kki], Sc[nt][nq], 0, 0, 0);
                __builtin_amdgcn_s_setprio(0);
            }
        }

        // --- per 32-key half: exp2 + lane-local pack -> bp, then PV ---
#pragma unroll
        for (int kki = 0; kki < 2; kki++) {
            f16x8_t bp[4];
#pragma unroll
            for (int nq = 0; nq < 4; nq++)
#pragma unroll
                for (int h = 0; h < 2; h++) {
                    const int nt = 2 * kki + h;
#pragma unroll
                    for (int i = 0; i < 4; i++) {
                        float p = __builtin_amdgcn_exp2f(Sc[nt][nq][i]);
                        sumacc[nq] += p;
                        bp[nq][h * 4 + i] = (f16)p;
                    }
                }
            // O^T += V^T P^T over this 32-key half; permuted token order
            // makes the lane's 8 keys one contiguous swizzled granule.
#pragma unroll
            for (int mt = 0; mt < 4; mt++) {
                const int d = mt * 16 + m16;
                f16x8_t av = *(const f16x8_t*)&Vc[d * 64 + KSW(d, kki * 4 + quad) * 8];
                __builtin_amdgcn_s_setprio(1);
#pragma unroll
                for (int nq = 0; nq < 4; nq++)
                    Oc[mt][nq] = __builtin_amdgcn_mfma_f32_16x16x32_f16(
                        av, bp[nq], Oc[mt][nq], 0, 0, 0);
                __builtin_amdgcn_s_setprio(0);
            }
        }

        // drain own next-tile loads, then one barrier publishes all staging
        asm volatile("s_waitcnt vmcnt(0)" ::: "memory");
        __builtin_amdgcn_s_barrier();
        asm volatile("" ::: "memory");
    }

    // --- l reduction across quads (lanes sharing m16), epilogue ---
    const int b = bh >> 4, h = bh & 15;
#pragma unroll
    for (int nq = 0; nq < 4; nq++) {
        float l = sumacc[nq];
        l += __shfl_xor(l, 16);
        l += __shfl_xor(l, 32);
        const float invl = 1.0f / l;
        const int s = s0 + wave * 64 + nq * 16 + m16;
        const size_t off = ((size_t)(b * SEQ + s)) * D_MODEL + h * HEAD_DIM;
#pragma unroll
        for (int mt = 0; mt < 4; mt++) {
            f16x4_t o4;
#pragma unroll
            for (int i = 0; i < 4; i++)
                o4[i] = (f16)(Oc[mt][nq][i] * invl);
            *(f16x4_t*)&Of[off + mt * 16 + quad * 4] = o4;
        }
    }
}

// ---------------------------------------------------------------------------
extern "C" void kernel_launch(void* const* d_in, const int* in_sizes, int n_in,
                              void* d_out, int out_size, void* d_ws, size_t ws_size,
                              hipStream_t stream) {
    const float* X    = (const float*)d_in[0];
    const float* Wqkv = (const float*)d_in[1];
    const float* bqkv = (const float*)d_in[2];
    const float* Wout = (const float*)d_in[3];
    const float* bout = (const float*)d_in[4];
    float* out = (float*)d_out;

    char* w8 = (char*)d_ws;
    const size_t MB = 1024 * 1024;
    f16* Xf  = (f16*)(w8);                 // 16 MB
    f16* Wqf = (f16*)(w8 + 16 * MB);       // 6 MB
    f16* Wof = (f16*)(w8 + 22 * MB);       // 2 MB
    f16* Qf  = (f16*)(w8 + 24 * MB);       // 16 MB
    f16* Kf  = (f16*)(w8 + 40 * MB);       // 16 MB
    f16* VfT = (f16*)(w8 + 56 * MB);       // 16 MB, (B,H,Dh,S) perm-tokens
    f16* Of  = (f16*)(w8 + 72 * MB);       // 16 MB
    float* cosT = (float*)(w8 + 88 * MB);  // 256 KB
    float* sinT = cosT + SEQ * 32;         // 256 KB

    prep_kernel<<<(N_CONV + SEQ * 32) / 256, 256, 0, stream>>>(
        X, Wqkv, Wout, Xf, Wqf, Wof, cosT, sinT);

    qkv_gemm_kernel<<<dim3(3 * D_MODEL / 128, TOKENS / 256), 512, 0, stream>>>(
        Xf, Wqf, bqkv, Qf, Kf, VfT, cosT, sinT);
    attn_kernel<<<64 * (SEQ / 256), 256, 0, stream>>>(Qf, Kf, VfT, Of);
    out_gemm_kernel<<<dim3(D_MODEL / 128, TOKENS / 128), 256, 0, stream>>>(
        Of, Wof, bout, out);
}